// Round 9
// baseline (113.549 us; speedup 1.0000x reference)
//
#include <hip/hip_runtime.h>

typedef __bf16 bf16;
typedef __bf16 bf16x8 __attribute__((ext_vector_type(8)));
typedef float  f32x4  __attribute__((ext_vector_type(4)));
typedef float  f32x16 __attribute__((ext_vector_type(16)));
typedef unsigned int u32x4 __attribute__((ext_vector_type(4)));

#define KK     9
#define KDIM   2304
#define KSTEPS 144           // KDIM / 16  (K-steps of the 32x32x16 MFMA)
#define PXW    64            // pixels per WG

__device__ __forceinline__ int sreadi(int v) {
    return __builtin_amdgcn_readfirstlane(v);
}

// bf16 pair unpack (uint = 2 packed bf16)
__device__ __forceinline__ float BL(unsigned v) {
    return __builtin_bit_cast(float, v << 16);
}
__device__ __forceinline__ float BH(unsigned v) {
    return __builtin_bit_cast(float, v & 0xffff0000u);
}

// ---------------------------------------------------------------------------
// prep2_k: unchanged (verified rounds 4-6).
// ---------------------------------------------------------------------------
__global__ __launch_bounds__(256) void prep2_k(const float* __restrict__ x,
                                               const float* __restrict__ w,
                                               bf16* __restrict__ xt,
                                               bf16* __restrict__ wq) {
    __shared__ __align__(16) char smem[8 * 2308 * 2];   // 36928 B, aliased
    int bid = blockIdx.x;
    int tid = threadIdx.x;
    if (bid < 1024) {
        float (*tileF)[65] = reinterpret_cast<float(*)[65]>(smem); // 16640 B
        int pt = bid & 63, ct = (bid >> 6) & 3, b = bid >> 8;
        const float* src = x + ((size_t)(b * 256 + ct * 64)) * 4096 + pt * 64;
        int f4 = tid & 15;           // pixel quad
        int cl = tid >> 4;           // channel (base)
        #pragma unroll
        for (int q = 0; q < 4; ++q) {
            int c = q * 16 + cl;
            f32x4 v = *reinterpret_cast<const f32x4*>(src + (size_t)c * 4096 + f4 * 4);
            tileF[f4 * 4 + 0][c] = v[0];
            tileF[f4 * 4 + 1][c] = v[1];
            tileF[f4 * 4 + 2][c] = v[2];
            tileF[f4 * 4 + 3][c] = v[3];
        }
        __syncthreads();
        int j = tid & 7, p0 = tid >> 3;
        bf16* dst = xt + ((size_t)(b * 4096 + pt * 64)) * 256 + ct * 64 + j * 8;
        #pragma unroll
        for (int pp = 0; pp < 2; ++pp) {
            int p = p0 + pp * 32;
            bf16x8 sv;
            #pragma unroll
            for (int k = 0; k < 8; ++k) sv[k] = (bf16)tileF[p][j * 8 + k];
            *reinterpret_cast<bf16x8*>(dst + (size_t)p * 256) = sv;
        }
    } else {
        bf16 (*Wl)[2308] = reinterpret_cast<bf16(*)[2308]>(smem);  // 36928 B
        int wb     = bid - 1024;        // 0..31
        int o_base = wb * 8;
        int m      = o_base >> 5;
        int o31b   = o_base & 31;
        // stage 8 o-rows (coalesced float4) as bf16 in LDS
        #pragma unroll
        for (int pass = 0; pass < 18; ++pass) {
            int i    = pass * 256 + tid;        // < 4608 float4
            int r    = i / 576;
            int col4 = i - r * 576;
            f32x4 v = *reinterpret_cast<const f32x4*>(
                w + (size_t)(o_base + r) * KDIM + col4 * 4);
            Wl[r][col4 * 4 + 0] = (bf16)v[0];
            Wl[r][col4 * 4 + 1] = (bf16)v[1];
            Wl[r][col4 * 4 + 2] = (bf16)v[2];
            Wl[r][col4 * 4 + 3] = (bf16)v[3];
        }
        __syncthreads();
        // compose + store 2304 granules (9 per thread), coalesced in wq
        #pragma unroll
        for (int pass = 0; pass < 9; ++pass) {
            int gid  = pass * 256 + tid;        // < 2304
            int ol   = gid & 7;
            int half = (gid >> 3) & 1;
            int ks   = gid >> 4;                // 0..143
            int kb   = ks * 16 + half * 8;
            int tap  = kb >> 8;
            int cc0  = kb & 255;
            bf16x8 sv;
            #pragma unroll
            for (int j = 0; j < 8; ++j) sv[j] = Wl[ol][(cc0 + j) * 9 + tap];
            size_t g = (size_t)((m * KSTEPS + ks) * 64 + half * 32 + o31b + ol);
            *reinterpret_cast<bf16x8*>(wq + g * 8) = sv;
        }
    }
}

// ---------------------------------------------------------------------------
// deform_gemm_k v9 "ring3": r6 geometry and code (PXW=64, grid 256 =
// 1 WG/CU, 16 waves, wave = mt x 64px x K-half kh, acc = 2 x f32x16;
// sampling bodies and GEMM VERBATIM from the verified r6 kernel) with a
// 3-buffer LDS ring replacing the 2-buffer same-tap schedule:
//   prologue: body(tap0)->S[0], body(tap1)->S[1], barrier
//   iter t:   af[8] A-frag prefetch(tap t)
//             body(tap t+2) -> S[(t+2)%3]     (t < KK-2)
//             GEMM(t) on S[t%3]
//             __syncthreads()
// Why: in r6, GEMM(t) depends on barrier(t) which depends on body(t) ->
// body's ~400cy gather wait is exposed every tap. In the ring, GEMM(t)'s
// buffer was finalized two barriers ago -> body(t+2) and GEMM(t) are
// independent in one basic block; the scheduler hoists the gathers and
// fills their wait with MFMAs/ds_reads. NO cross-iteration register state
// (the r7/r8 issue/combine split that failed twice is NOT used; bodies
// are whole, r6-verbatim).
// Race-freedom (1 barrier/iter, 3 buffers): write S[(t+2)%3] at iter t;
// previous reader GEMM(t-1) used the same buffer and is separated by
// barrier(t-1); reader GEMM(t) follows writer body at t-2 across barriers
// t-2 and t-1. Epilogue Sf (64 KB) reuses S[0..1] after the final barrier.
// Granule-XOR swizzle (0 conflicts r1-r6), kh-epilogue LDS reduction,
// XCD band swizzle, tap rotation: unchanged.
// ---------------------------------------------------------------------------
__global__ __launch_bounds__(1024, 4) void deform_gemm_k(
    const bf16*  __restrict__ xt,
    const float* __restrict__ off,
    const bf16*  __restrict__ wq,
    const float* __restrict__ bias,
    float*       __restrict__ out) {

    __shared__ bf16 S[3][PXW * 256];   // 3 x 32 KB ring, swizzled granules

    int tid   = threadIdx.x;
    int wavei = sreadi(tid >> 6);   // 0..15
    int lane  = tid & 63;
    int l32   = lane & 31;
    int half  = lane >> 5;
    int mt    = wavei & 7;          // mtile (32 output channels)
    int kh    = wavei >> 3;         // K-half within each tap

    int bid   = blockIdx.x;                      // 0..255
    int pb    = ((bid & 7) << 5) | (bid >> 3);   // XCD-band pixel-block
    int pix0  = pb * PXW;
    int b     = pix0 >> 12;                      // WG-uniform batch
    int pimgb = pix0 & 4095;
    int obase = b * 73728;                       // base into off[]
    int rot   = (bid >> 3) & 7;                  // tap-phase desync across CUs

    // sampling geometry: this lane serves rows n0, n1
    int n0    = wavei * 4 + half * 2;
    int n1    = n0 + 1;
    int pimg0 = pimgb + n0;
    int pimg1 = pimgb + n1;
    const char* xb = (const char*)xt + ((size_t)b << 21) + l32 * 16;

    f32x16 acc0, acc1;
    #pragma unroll
    for (int r = 0; r < 16; ++r) { acc0[r] = 0.f; acc1[r] = 0.f; }

    // one sampling body: row n / pixel pimg for tap geometry (ty,tx),
    // offsets loaded inline -- VERBATIM r6 math
    auto body = [&](int n, int pimg, float oy, float ox, int ty, int tx,
                    bf16* Sw) {
        float py = (float)((pimg >> 6) + ty) + oy;
        float px = (float)((pimg & 63) + tx) + ox;
        float fy = floorf(py), fx = floorf(px);
        int   y0 = (int)fy,    x0 = (int)fx;
        float wy1 = py - fy, wx1 = px - fx;
        float wy0 = 1.f - wy1, wx0 = 1.f - wx1;
        wy0 = ((unsigned)y0       < 64u) ? wy0 : 0.f;
        wy1 = ((unsigned)(y0 + 1) < 64u) ? wy1 : 0.f;
        wx0 = ((unsigned)x0       < 64u) ? wx0 : 0.f;
        wx1 = ((unsigned)(x0 + 1) < 64u) ? wx1 : 0.f;
        int yc0 = min(max(y0, 0), 63), yc1 = min(max(y0 + 1, 0), 63);
        int xc0 = min(max(x0, 0), 63), xc1 = min(max(x0 + 1, 0), 63);
        unsigned u0 = (unsigned)(yc0 * 64 + xc0) * 512u;
        unsigned u1 = (unsigned)(yc0 * 64 + xc1) * 512u;
        unsigned u2 = (unsigned)(yc1 * 64 + xc0) * 512u;
        unsigned u3 = (unsigned)(yc1 * 64 + xc1) * 512u;
        float w0 = wy0 * wx0, w1 = wy0 * wx1;
        float w2 = wy1 * wx0, w3 = wy1 * wx1;
        u32x4 g0 = *(const u32x4*)(xb + u0);
        u32x4 g1 = *(const u32x4*)(xb + u1);
        u32x4 g2 = *(const u32x4*)(xb + u2);
        u32x4 g3 = *(const u32x4*)(xb + u3);
        bf16x8 sv;
        #pragma unroll
        for (int q = 0; q < 4; ++q) {
            float lo = fmaf(w0, BL(g0[q]), fmaf(w1, BL(g1[q]),
                       fmaf(w2, BL(g2[q]),      w3 * BL(g3[q]))));
            float hi = fmaf(w0, BH(g0[q]), fmaf(w1, BH(g1[q]),
                       fmaf(w2, BH(g2[q]),      w3 * BH(g3[q]))));
            sv[q * 2]     = (bf16)lo;
            sv[q * 2 + 1] = (bf16)hi;
        }
        int gsw = l32 ^ (n & 31);              // granule-XOR swizzle
        *reinterpret_cast<bf16x8*>(Sw + n * 256 + gsw * 8) = sv;
    };

    // whole-tap body: both rows, offsets loaded inline
    auto tap_body = [&](int tp, bf16* Sw) {
        int ty = tp / 3 - 1;
        int tx = tp % 3 - 1;
        float oy0 = off[obase + (2 * tp)     * 4096 + pimg0];
        float ox0 = off[obase + (2 * tp + 1) * 4096 + pimg0];
        float oy1 = off[obase + (2 * tp)     * 4096 + pimg1];
        float ox1 = off[obase + (2 * tp + 1) * 4096 + pimg1];
        body(n0, pimg0, oy0, ox0, ty, tx, Sw);
        body(n1, pimg1, oy1, ox1, ty, tx, Sw);
    };

    // ---- prologue: fill S[0] (tap 0) and S[1] (tap 1) ----
    {
        int tp0 = rot;                               // tap(0)
        tap_body(tp0, &S[0][0]);
        int tp1 = rot + 1; if (tp1 >= KK) tp1 -= KK; // tap(1)
        tap_body(tp1, &S[1][0]);
    }
    __syncthreads();

    int br = 0, bw = 2;          // read buffer = t%3, write buffer = (t+2)%3
    for (int t = 0; t < KK; ++t) {
        int tap = t + rot; if (tap >= KK) tap -= KK;

        // A-frag prefetch for tap(t): latency covered by body + GEMM
        const bf16* ap0 = wq +
            ((size_t)(((mt * KSTEPS) + tap * 16 + kh * 8) * 64 + lane)) * 8;
        bf16x8 af[8];
        #pragma unroll
        for (int s = 0; s < 8; ++s)
            af[s] = *reinterpret_cast<const bf16x8*>(ap0 + (size_t)s * 512);

        // sample tap(t+2) into the ring's write buffer (independent of
        // GEMM(t) below -> scheduler interleaves, gather wait filled)
        if (t < KK - 2) {
            int tp = tap + 2; if (tp >= KK) tp -= KK;
            tap_body(tp, &S[bw][0]);
        }

        // ---- GEMM(t) on S[t%3]: this wave's K-half x 64 px ----
        const bf16* Sr = &S[br][0];
        #pragma unroll
        for (int s = 0; s < 8; ++s) {
            int g  = (kh * 8 + s) * 2 + half;   // 16B granule (cin base >> 3)
            int gs = g ^ l32;                   // row & 31 == l32 for both nt
            bf16x8 b0 = *reinterpret_cast<const bf16x8*>(Sr + l32 * 256 + gs * 8);
            bf16x8 b1 = *reinterpret_cast<const bf16x8*>(Sr + (32 + l32) * 256 + gs * 8);
            acc0 = __builtin_amdgcn_mfma_f32_32x32x16_bf16(af[s], b0, acc0, 0, 0, 0);
            acc1 = __builtin_amdgcn_mfma_f32_32x32x16_bf16(af[s], b1, acc1, 0, 0, 0);
        }

        __syncthreads();
        br = (br + 1 == 3) ? 0 : br + 1;
        bw = (bw + 1 == 3) ? 0 : bw + 1;
    }

    // ---- epilogue: sum the two K-halves through LDS, then store ----
    float* Sf = reinterpret_cast<float*>(&S[0][0]);   // 16384 f32 = 64 KB
    if (kh == 1) {
        #pragma unroll
        for (int r = 0; r < 16; ++r) {
            Sf[((mt * 2 + 0) * 16 + r) * 64 + lane] = acc0[r];
            Sf[((mt * 2 + 1) * 16 + r) * 64 + lane] = acc1[r];
        }
    }
    __syncthreads();
    if (kh == 0) {
        // C/D layout (32x32x16): col = lane&31, row = (r&3)+8*(r>>2)+4*half
        int m = mt * 32;
        #pragma unroll
        for (int nt = 0; nt < 2; ++nt) {
            int px = pimgb + nt * 32 + l32;
            float* op = out + ((size_t)(b * 256 + m)) * 4096 + px;
            #pragma unroll
            for (int r = 0; r < 16; ++r) {
                int row = (r & 3) + 8 * (r >> 2) + half * 4;
                float a = (nt == 0) ? acc0[r] : acc1[r];
                float v = a + Sf[((mt * 2 + nt) * 16 + r) * 64 + lane]
                            + bias[m + row];
                op[(size_t)row * 4096] = v;
            }
        }
    }
}

// ---------------------------------------------------------------------------
extern "C" void kernel_launch(void* const* d_in, const int* in_sizes, int n_in,
                              void* d_out, int out_size, void* d_ws, size_t ws_size,
                              hipStream_t stream) {
    const float* x    = (const float*)d_in[0];   // [4,256,64,64]
    const float* off  = (const float*)d_in[1];   // [4,18,64,64]
    const float* w    = (const float*)d_in[2];   // [256,256,3,3]
    const float* bias = (const float*)d_in[3];   // [256]
    float* out = (float*)d_out;                  // [4,256,64,64]

    bf16* wq = (bf16*)d_ws;                               // 1,179,648 B
    bf16* xt = (bf16*)((char*)d_ws + (size_t)589824 * 2); // 8,388,608 B

    prep2_k<<<1056, 256, 0, stream>>>(x, w, xt, wq);
    deform_gemm_k<<<256, 1024, 0, stream>>>(xt, off, wq, bias, out);
}